// Round 2
// baseline (332.883 us; speedup 1.0000x reference)
//
#include <hip/hip_runtime.h>
#include <hip/hip_bf16.h>

#define NN 100000
#define EE 1200000
#define F1 128
#define F2 256
#define F3 40
#define MROWS 64
#define NBUK ((NN + 255) / 256)          // 391 coarse buckets (256 nodes each)
#define NBLK 256                         // radix blocks
#define CHUNK ((EE + NBLK - 1) / NBLK)   // 4688 edges per block
#define DCAP 4096                        // max records per bucket (mean 3070, +18 sigma)
#define XB2 ((NN * 32 + 255) / 256)      // 12500 blocks for x-prep (float4 granularity)

typedef __bf16 bf16x8 __attribute__((ext_vector_type(8)));
typedef float  f32x4  __attribute__((ext_vector_type(4)));

__device__ __forceinline__ unsigned short f2bf(float f) {   // RNE bf16
    unsigned u = __float_as_uint(f);
    return (unsigned short)((u + 0x7fffu + ((u >> 16) & 1u)) >> 16);
}
__device__ __forceinline__ float bflo(unsigned v) { return __uint_as_float(v << 16); }
__device__ __forceinline__ float bfhi(unsigned v) { return __uint_as_float(v & 0xffff0000u); }

// ---- pass A: per-(bin,block) coarse histogram only (no global atomics) ----
__global__ __launch_bounds__(256) void k_hist(const int* __restrict__ col,
                                              int* __restrict__ hist) {
    __shared__ int lh[NBUK];
    for (int i = threadIdx.x; i < NBUK; i += 256) lh[i] = 0;
    __syncthreads();
    int e0 = blockIdx.x * CHUNK;
    int e1 = min(e0 + CHUNK, EE);
    for (int e = e0 + threadIdx.x; e < e1; e += 256) {
        int c = col[e];
        if ((unsigned)c < (unsigned)NN) atomicAdd(&lh[c >> 8], 1);
    }
    __syncthreads();
    for (int i = threadIdx.x; i < NBUK; i += 256) hist[i * NBLK + blockIdx.x] = lh[i];
}

// ---- pass B1: scan each bin's 256 per-block counts; bintot per bin ----
__global__ __launch_bounds__(256) void k_scanbin(int* __restrict__ hist,
                                                 int* __restrict__ bintot) {
    __shared__ int s[NBLK];
    int b = blockIdx.x;
    int v = hist[b * NBLK + threadIdx.x];
    s[threadIdx.x] = v;
    __syncthreads();
    int acc = v;
    for (int d = 1; d < NBLK; d <<= 1) {
        int add = (threadIdx.x >= d) ? s[threadIdx.x - d] : 0;
        __syncthreads();
        acc += add;
        s[threadIdx.x] = acc;
        __syncthreads();
    }
    hist[b * NBLK + threadIdx.x] = acc - v;   // exclusive within bin
    if (threadIdx.x == NBLK - 1) bintot[b] = acc;
}

// ---- pass B2: exclusive scan of bin totals -> binbase[NBUK+1] ----
__global__ __launch_bounds__(512) void k_scanbase(const int* __restrict__ bintot,
                                                  int* __restrict__ binbase) {
    __shared__ int s[512];
    int v = (threadIdx.x < NBUK) ? bintot[threadIdx.x] : 0;
    s[threadIdx.x] = v;
    __syncthreads();
    int acc = v;
    for (int d = 1; d < 512; d <<= 1) {
        int add = (threadIdx.x >= d) ? s[threadIdx.x - d] : 0;
        __syncthreads();
        acc += add;
        s[threadIdx.x] = acc;
        __syncthreads();
    }
    if (threadIdx.x < NBUK) binbase[threadIdx.x] = acc - v;
    if (threadIdx.x == NBUK - 1) binbase[NBUK] = acc;
}

// ---- pass C: scatter records into block-private runs per bin ----
__global__ __launch_bounds__(256) void k_scat(const int* __restrict__ row,
                                              const int* __restrict__ col,
                                              const int* __restrict__ hist,
                                              const int* __restrict__ binbase,
                                              unsigned* __restrict__ rec) {
    __shared__ int lcur[NBUK];
    for (int i = threadIdx.x; i < NBUK; i += 256)
        lcur[i] = binbase[i] + hist[i * NBLK + blockIdx.x];
    __syncthreads();
    int e0 = blockIdx.x * CHUNK;
    int e1 = min(e0 + CHUNK, EE);
    for (int e = e0 + threadIdx.x; e < e1; e += 256) {
        int r = row[e], c = col[e];
        if ((unsigned)c < (unsigned)NN) {
            int pos = atomicAdd(&lcur[c >> 8], 1);   // LDS atomic
            rec[pos] = ((unsigned)r & 0xFFFFFFu) | ((unsigned)(c & 255) << 24);
        }
    }
}

// ---- pass D: bucket -> CSR; derive cnt via LDS histogram; cursor(end) + dinv ----
__global__ __launch_bounds__(256) void k_csr(const int* __restrict__ binbase,
                                             const unsigned* __restrict__ rec,
                                             int* __restrict__ eidx,
                                             int* __restrict__ cnt,
                                             int* __restrict__ cursor,
                                             float* __restrict__ dinv) {
    __shared__ int lcnt[256];
    __shared__ int s[256];
    __shared__ int lcur[256];
    __shared__ int lde[DCAP];
    const int b = blockIdx.x;
    const int tid = threadIdx.x;
    lcnt[tid] = 0;
    __syncthreads();
    const int base = binbase[b];
    const int nb = min(binbase[b + 1] - base, DCAP);
    for (int j = tid; j < nb; j += 256) atomicAdd(&lcnt[rec[base + j] >> 24], 1);
    __syncthreads();
    int cv = lcnt[tid];
    s[tid] = cv;
    __syncthreads();
    int acc = cv;
    for (int d = 1; d < 256; d <<= 1) {
        int add = (tid >= d) ? s[tid - d] : 0;
        __syncthreads();
        acc += add;
        s[tid] = acc;
        __syncthreads();
    }
    int excl = acc - cv;
    lcur[tid] = excl;
    const int node = (b << 8) + tid;
    if (node < NN) {
        cnt[node] = cv;
        cursor[node] = base + excl + cv;            // END cursor (start = end - cnt)
        dinv[node] = rsqrtf((float)(cv + 1));       // +1 self-loop
    }
    __syncthreads();
    for (int j = tid; j < nb; j += 256) {
        unsigned v = rec[base + j];
        int pos = atomicAdd(&lcur[v >> 24], 1);     // LDS atomic
        lde[pos] = (int)(v & 0xFFFFFFu);
    }
    __syncthreads();
    for (int j = tid; j < nb; j += 256) eidx[base + j] = lde[j];
}

// ---- fused prep: xh[i] = bf16(x[i]*dinv[i]) ; pack W1,W2. float4-vectorized ----
__global__ void k_prep(const float4* __restrict__ x, const float* __restrict__ dinv,
                       uint2* __restrict__ xh,
                       const float* __restrict__ W1, const float* __restrict__ W2,
                       __hip_bfloat16* __restrict__ W1p, __hip_bfloat16* __restrict__ W2p) {
    if (blockIdx.x < XB2) {
        int idx = blockIdx.x * 256 + threadIdx.x;   // NN*32 float4s, exact multiple
        float d = dinv[idx >> 5];
        float4 v = x[idx];
        uint2 o;
        o.x = (unsigned)f2bf(v.x * d) | ((unsigned)f2bf(v.y * d) << 16);
        o.y = (unsigned)f2bf(v.z * d) | ((unsigned)f2bf(v.w * d) << 16);
        xh[idx] = o;
    } else {
        int idx = (blockIdx.x - XB2) * 256 + threadIdx.x;
        if (idx < F1 * F2) {
            int k = idx / F2, col = idx - (idx / F2) * F2;
            int k8 = k >> 3, j = k & 7;
            W1p[((size_t)(k8 * F2 + col) << 3) + j] = __float2bfloat16(W1[(size_t)k * F2 + col]);
        } else if (idx < F1 * F2 + F2 * 48) {
            int i2 = idx - F1 * F2;
            int k = i2 / 48, col = i2 - (i2 / 48) * 48;
            int k8 = k >> 3, j = k & 7;
            float v = (col < F3) ? W2[(size_t)k * F3 + col] : 0.0f;
            W2p[((size_t)(k8 * 48 + col) << 3) + j] = __float2bfloat16(v);
        }
    }
}

// ---- layer-1 pull aggregation, feature-phased (p=0: feat 0..63, p=1: 64..127).
// 8 groups of 8 lanes; each group walks edges k ≡ g (mod 8) with dwordx4 gathers:
// one load instruction covers 8 edge-rows x 128B (one L2 line each). Working set
// per phase = 12.8 MB (vs 25.6) -> better per-XCD L2 hit on the random gather. ----
__global__ __launch_bounds__(256) void k_agg1(const int* __restrict__ cursor,
                                              const int* __restrict__ cnt,
                                              const int* __restrict__ eidx,
                                              const float* __restrict__ dinv,
                                              const unsigned* __restrict__ xh,
                                              unsigned* __restrict__ agg,
                                              int p) {
    int node = blockIdx.x * 4 + (threadIdx.x >> 6);
    if (node >= NN) return;
    const int lane = threadIdx.x & 63;
    const int g = lane >> 3, t = lane & 7;
    const uint4* __restrict__ xb = (const uint4*)(xh + p * 32) + t;  // elem i -> xh + p*32 + 16i + 4t

    float a0 = 0.f, a1 = 0.f, a2 = 0.f, a3 = 0.f, a4 = 0.f, a5 = 0.f, a6 = 0.f, a7 = 0.f;
    if (g == 0) {                                  // self-loop term
        uint4 v = xb[(size_t)node << 4];
        a0 = bflo(v.x); a1 = bfhi(v.x); a2 = bflo(v.y); a3 = bfhi(v.y);
        a4 = bflo(v.z); a5 = bfhi(v.z); a6 = bflo(v.w); a7 = bfhi(v.w);
    }
    const int n = cnt[node];
    const int s = cursor[node] - n;
    int k = g;
    for (; k + 8 < n; k += 16) {                   // 2 gathers in flight per lane
        int r0 = eidx[s + k];
        int r1 = eidx[s + k + 8];
        uint4 v0 = xb[(size_t)r0 << 4];
        uint4 v1 = xb[(size_t)r1 << 4];
        a0 += bflo(v0.x); a1 += bfhi(v0.x); a2 += bflo(v0.y); a3 += bfhi(v0.y);
        a4 += bflo(v0.z); a5 += bfhi(v0.z); a6 += bflo(v0.w); a7 += bfhi(v0.w);
        a0 += bflo(v1.x); a1 += bfhi(v1.x); a2 += bflo(v1.y); a3 += bfhi(v1.y);
        a4 += bflo(v1.z); a5 += bfhi(v1.z); a6 += bflo(v1.w); a7 += bfhi(v1.w);
    }
    if (k < n) {                                   // at most one leftover per group
        int r0 = eidx[s + k];
        uint4 v0 = xb[(size_t)r0 << 4];
        a0 += bflo(v0.x); a1 += bfhi(v0.x); a2 += bflo(v0.y); a3 += bfhi(v0.y);
        a4 += bflo(v0.z); a5 += bfhi(v0.z); a6 += bflo(v0.w); a7 += bfhi(v0.w);
    }
    // butterfly-reduce across the 8 groups (lane bits 3..5)
#pragma unroll
    for (int off = 8; off < 64; off <<= 1) {
        a0 += __shfl_xor(a0, off); a1 += __shfl_xor(a1, off);
        a2 += __shfl_xor(a2, off); a3 += __shfl_xor(a3, off);
        a4 += __shfl_xor(a4, off); a5 += __shfl_xor(a5, off);
        a6 += __shfl_xor(a6, off); a7 += __shfl_xor(a7, off);
    }
    if (g == 0) {
        float d = dinv[node];
        uint4 o;
        o.x = (unsigned)f2bf(a0 * d) | ((unsigned)f2bf(a1 * d) << 16);
        o.y = (unsigned)f2bf(a2 * d) | ((unsigned)f2bf(a3 * d) << 16);
        o.z = (unsigned)f2bf(a4 * d) | ((unsigned)f2bf(a5 * d) << 16);
        o.w = (unsigned)f2bf(a6 * d) | ((unsigned)f2bf(a7 * d) << 16);
        *(uint4*)(agg + ((size_t)node << 6) + p * 32 + (t << 2)) = o;
    }
}

// ---- fused MFMA GEMM1 + ReLU + GEMM2; tg rows padded to 64 bf16 (one line) ----
__global__ __launch_bounds__(256) void k_gemm_mfma(
    const __hip_bfloat16* __restrict__ agg, const __hip_bfloat16* __restrict__ W1p,
    const float* __restrict__ b1, const __hip_bfloat16* __restrict__ W2p,
    const float* __restrict__ dinv, unsigned short* __restrict__ tg) {
    __shared__ __hip_bfloat16 h_s[MROWS][F2 + 8];   // 33 KB
    const int i0   = blockIdx.x * MROWS;
    const int wave = threadIdx.x >> 6;
    const int lane = threadIdx.x & 63;
    const int m = lane & 15, q = lane >> 4;
    const int rowA = i0 + wave * 16 + m;

    f32x4 acc[16];
#pragma unroll
    for (int c = 0; c < 16; ++c) acc[c] = (f32x4){0.f, 0.f, 0.f, 0.f};

#pragma unroll
    for (int s = 0; s < 4; ++s) {           // k = 32s + 8q + j
        bf16x8 a;
#pragma unroll
        for (int j = 0; j < 8; ++j) a[j] = (__bf16)0.0f;
        if (rowA < NN) a = *(const bf16x8*)(agg + (size_t)rowA * F1 + s * 32 + q * 8);
        const __hip_bfloat16* bp = W1p + ((size_t)(4 * s + q) * F2) * 8;
#pragma unroll
        for (int c = 0; c < 16; ++c) {
            bf16x8 b = *(const bf16x8*)(bp + ((size_t)(c * 16 + m) << 3));
            acc[c] = __builtin_amdgcn_mfma_f32_16x16x32_bf16(a, b, acc[c], 0, 0, 0);
        }
    }

#pragma unroll
    for (int c = 0; c < 16; ++c) {
        int col = c * 16 + m;
        float bj = b1[col];
#pragma unroll
        for (int r = 0; r < 4; ++r) {
            int lr = wave * 16 + q * 4 + r;
            h_s[lr][col] = __float2bfloat16(fmaxf(acc[c][r] + bj, 0.0f));
        }
    }
    __syncthreads();

    f32x4 acc2[3];
#pragma unroll
    for (int c = 0; c < 3; ++c) acc2[c] = (f32x4){0.f, 0.f, 0.f, 0.f};

#pragma unroll
    for (int s = 0; s < 8; ++s) {
        bf16x8 a = *(const bf16x8*)(&h_s[wave * 16 + m][s * 32 + q * 8]);
        const __hip_bfloat16* bp = W2p + ((size_t)(4 * s + q) * 48) * 8;
#pragma unroll
        for (int c = 0; c < 3; ++c) {
            bf16x8 b = *(const bf16x8*)(bp + ((size_t)(c * 16 + m) << 3));
            acc2[c] = __builtin_amdgcn_mfma_f32_16x16x32_bf16(a, b, acc2[c], 0, 0, 0);
        }
    }

#pragma unroll
    for (int c = 0; c < 3; ++c) {
        int col = c * 16 + m;
        if (col < F3) {
#pragma unroll
            for (int r = 0; r < 4; ++r) {
                int grow = i0 + wave * 16 + q * 4 + r;
                if (grow < NN)
                    tg[((size_t)grow << 6) + col] = f2bf(acc2[c][r] * dinv[grow]);
            }
        }
    }
}

// ---- layer-2 pull aggregation: 8 line-rows in flight per wave ----
__global__ __launch_bounds__(256) void k_agg2(const int* __restrict__ cursor,
                                              const int* __restrict__ cnt,
                                              const int* __restrict__ eidx,
                                              const float* __restrict__ dinv,
                                              const unsigned short* __restrict__ tg,
                                              const float* __restrict__ b2,
                                              float* __restrict__ out) {
    int node = blockIdx.x * 4 + (threadIdx.x >> 6);
    int lane = threadIdx.x & 63;
    if (node >= NN || lane >= F3) return;
    float a = __uint_as_float((unsigned)tg[((size_t)node << 6) + lane] << 16);
    int n = cnt[node];
    int s = cursor[node] - n;
    int k = 0;
    for (; k + 7 < n; k += 8) {
        int r0 = eidx[s + k + 0], r1 = eidx[s + k + 1];
        int r2 = eidx[s + k + 2], r3 = eidx[s + k + 3];
        int r4 = eidx[s + k + 4], r5 = eidx[s + k + 5];
        int r6 = eidx[s + k + 6], r7 = eidx[s + k + 7];
        unsigned short w0 = tg[((size_t)r0 << 6) + lane];
        unsigned short w1 = tg[((size_t)r1 << 6) + lane];
        unsigned short w2 = tg[((size_t)r2 << 6) + lane];
        unsigned short w3 = tg[((size_t)r3 << 6) + lane];
        unsigned short w4 = tg[((size_t)r4 << 6) + lane];
        unsigned short w5 = tg[((size_t)r5 << 6) + lane];
        unsigned short w6 = tg[((size_t)r6 << 6) + lane];
        unsigned short w7 = tg[((size_t)r7 << 6) + lane];
        a += __uint_as_float((unsigned)w0 << 16);
        a += __uint_as_float((unsigned)w1 << 16);
        a += __uint_as_float((unsigned)w2 << 16);
        a += __uint_as_float((unsigned)w3 << 16);
        a += __uint_as_float((unsigned)w4 << 16);
        a += __uint_as_float((unsigned)w5 << 16);
        a += __uint_as_float((unsigned)w6 << 16);
        a += __uint_as_float((unsigned)w7 << 16);
    }
    for (; k + 3 < n; k += 4) {
        int r0 = eidx[s + k + 0], r1 = eidx[s + k + 1];
        int r2 = eidx[s + k + 2], r3 = eidx[s + k + 3];
        unsigned short w0 = tg[((size_t)r0 << 6) + lane];
        unsigned short w1 = tg[((size_t)r1 << 6) + lane];
        unsigned short w2 = tg[((size_t)r2 << 6) + lane];
        unsigned short w3 = tg[((size_t)r3 << 6) + lane];
        a += __uint_as_float((unsigned)w0 << 16);
        a += __uint_as_float((unsigned)w1 << 16);
        a += __uint_as_float((unsigned)w2 << 16);
        a += __uint_as_float((unsigned)w3 << 16);
    }
    for (; k < n; ++k)
        a += __uint_as_float((unsigned)tg[((size_t)eidx[s + k] << 6) + lane] << 16);
    out[(size_t)node * F3 + lane] = dinv[node] * a + b2[lane];
}

extern "C" void kernel_launch(void* const* d_in, const int* in_sizes, int n_in,
                              void* d_out, int out_size, void* d_ws, size_t ws_size,
                              hipStream_t stream) {
    const float* x  = (const float*)d_in[0];
    const int*   ei = (const int*)d_in[1];
    const float* W1 = (const float*)d_in[2];
    const float* b1 = (const float*)d_in[3];
    const float* W2 = (const float*)d_in[4];
    const float* b2 = (const float*)d_in[5];
    float* out = (float*)d_out;

    const int* row = ei;
    const int* col = ei + EE;

    // ws: cnt[N] | cursor[N] | dinv[N] | hist[NBUK*NBLK] | bintot | binbase
    //     | eidx[E] | xh[N*64 u32] | agg[N*64 u32] | W1p | W2p         ~58 MB
    // overlays: rec (E u32) on agg (dead until k_agg1); tg (N*64 bf16) on xh
    // (dead after k_agg1, written by k_gemm, read by k_agg2).
    // slack +9 (was +7): makes xh/agg/W1p 16B-aligned for uint4/bf16x8 loads.
    int* cnt     = (int*)d_ws;
    int* cursor  = cnt + NN;
    float* dinv  = (float*)(cursor + NN);
    int* hist    = (int*)(dinv + NN);
    int* bintot  = hist + NBUK * NBLK;
    int* binbase = bintot + NBUK;
    int* eidx    = binbase + (NBUK + 1) + 9;   // alignment slack -> xh % 16 == 0
    unsigned* xh  = (unsigned*)(eidx + EE);
    unsigned* agg = xh + (size_t)NN * 64;
    unsigned* rec = agg;                               // overlay
    unsigned short* tg = (unsigned short*)xh;          // overlay
    __hip_bfloat16* W1p = (__hip_bfloat16*)(agg + (size_t)NN * 64);
    __hip_bfloat16* W2p = W1p + (size_t)F1 * F2;

    k_hist    <<<NBLK, 256, 0, stream>>>(col, hist);
    k_scanbin <<<NBUK, NBLK, 0, stream>>>(hist, bintot);
    k_scanbase<<<1, 512, 0, stream>>>(bintot, binbase);
    k_scat    <<<NBLK, 256, 0, stream>>>(row, col, hist, binbase, rec);
    k_csr     <<<NBUK, 256, 0, stream>>>(binbase, rec, eidx, cnt, cursor, dinv);

    k_prep<<<XB2 + (F1 * F2 + F2 * 48 + 255) / 256, 256, 0, stream>>>(
        (const float4*)x, dinv, (uint2*)xh, W1, W2, W1p, W2p);

    k_agg1<<<(NN + 3) / 4, 256, 0, stream>>>(cursor, cnt, eidx, dinv, xh, agg, 0);
    k_agg1<<<(NN + 3) / 4, 256, 0, stream>>>(cursor, cnt, eidx, dinv, xh, agg, 1);
    k_gemm_mfma<<<(NN + MROWS - 1) / MROWS, 256, 0, stream>>>(
        (const __hip_bfloat16*)agg, W1p, b1, W2p, dinv, tg);
    k_agg2<<<(NN + 3) / 4, 256, 0, stream>>>(cursor, cnt, eidx, dinv, tg, b2, out);
}

// Round 3
// 280.379 us; speedup vs baseline: 1.1873x; 1.1873x over previous
//
#include <hip/hip_runtime.h>
#include <hip/hip_bf16.h>

#define NN 100000
#define EE 1200000
#define F1 128
#define F2 256
#define F3 40
#define MROWS 64
#define NBUK ((NN + 255) / 256)          // 391 coarse buckets (256 nodes each)
#define NBLK 256                         // radix blocks
#define CHUNK ((EE + NBLK - 1) / NBLK)   // 4688 edges per block
#define DCAP 4096                        // max records per bucket (mean 3070, +18 sigma)
#define XB2 ((NN * 32 + 255) / 256)      // 12500 blocks for x-prep (float4 granularity)

typedef __bf16 bf16x8 __attribute__((ext_vector_type(8)));
typedef float  f32x4  __attribute__((ext_vector_type(4)));

__device__ __forceinline__ unsigned short f2bf(float f) {   // RNE bf16
    unsigned u = __float_as_uint(f);
    return (unsigned short)((u + 0x7fffu + ((u >> 16) & 1u)) >> 16);
}
__device__ __forceinline__ float bflo(unsigned v) { return __uint_as_float(v << 16); }
__device__ __forceinline__ float bfhi(unsigned v) { return __uint_as_float(v & 0xffff0000u); }

// ---- pass A: per-(bin,block) coarse histogram only (no global atomics) ----
__global__ __launch_bounds__(256) void k_hist(const int* __restrict__ col,
                                              int* __restrict__ hist) {
    __shared__ int lh[NBUK];
    for (int i = threadIdx.x; i < NBUK; i += 256) lh[i] = 0;
    __syncthreads();
    int e0 = blockIdx.x * CHUNK;
    int e1 = min(e0 + CHUNK, EE);
    for (int e = e0 + threadIdx.x; e < e1; e += 256) {
        int c = col[e];
        if ((unsigned)c < (unsigned)NN) atomicAdd(&lh[c >> 8], 1);
    }
    __syncthreads();
    for (int i = threadIdx.x; i < NBUK; i += 256) hist[i * NBLK + blockIdx.x] = lh[i];
}

// ---- pass B1: scan each bin's 256 per-block counts; bintot per bin ----
__global__ __launch_bounds__(256) void k_scanbin(int* __restrict__ hist,
                                                 int* __restrict__ bintot) {
    __shared__ int s[NBLK];
    int b = blockIdx.x;
    int v = hist[b * NBLK + threadIdx.x];
    s[threadIdx.x] = v;
    __syncthreads();
    int acc = v;
    for (int d = 1; d < NBLK; d <<= 1) {
        int add = (threadIdx.x >= d) ? s[threadIdx.x - d] : 0;
        __syncthreads();
        acc += add;
        s[threadIdx.x] = acc;
        __syncthreads();
    }
    hist[b * NBLK + threadIdx.x] = acc - v;   // exclusive within bin
    if (threadIdx.x == NBLK - 1) bintot[b] = acc;
}

// ---- pass B2: exclusive scan of bin totals -> binbase[NBUK+1] ----
__global__ __launch_bounds__(512) void k_scanbase(const int* __restrict__ bintot,
                                                  int* __restrict__ binbase) {
    __shared__ int s[512];
    int v = (threadIdx.x < NBUK) ? bintot[threadIdx.x] : 0;
    s[threadIdx.x] = v;
    __syncthreads();
    int acc = v;
    for (int d = 1; d < 512; d <<= 1) {
        int add = (threadIdx.x >= d) ? s[threadIdx.x - d] : 0;
        __syncthreads();
        acc += add;
        s[threadIdx.x] = acc;
        __syncthreads();
    }
    if (threadIdx.x < NBUK) binbase[threadIdx.x] = acc - v;
    if (threadIdx.x == NBUK - 1) binbase[NBUK] = acc;
}

// ---- pass C: scatter records into block-private runs per bin ----
__global__ __launch_bounds__(256) void k_scat(const int* __restrict__ row,
                                              const int* __restrict__ col,
                                              const int* __restrict__ hist,
                                              const int* __restrict__ binbase,
                                              unsigned* __restrict__ rec) {
    __shared__ int lcur[NBUK];
    for (int i = threadIdx.x; i < NBUK; i += 256)
        lcur[i] = binbase[i] + hist[i * NBLK + blockIdx.x];
    __syncthreads();
    int e0 = blockIdx.x * CHUNK;
    int e1 = min(e0 + CHUNK, EE);
    for (int e = e0 + threadIdx.x; e < e1; e += 256) {
        int r = row[e], c = col[e];
        if ((unsigned)c < (unsigned)NN) {
            int pos = atomicAdd(&lcur[c >> 8], 1);   // LDS atomic
            rec[pos] = ((unsigned)r & 0xFFFFFFu) | ((unsigned)(c & 255) << 24);
        }
    }
}

// ---- pass D: bucket -> CSR; derive cnt via LDS histogram; cursor(end) + dinv ----
__global__ __launch_bounds__(256) void k_csr(const int* __restrict__ binbase,
                                             const unsigned* __restrict__ rec,
                                             int* __restrict__ eidx,
                                             int* __restrict__ cnt,
                                             int* __restrict__ cursor,
                                             float* __restrict__ dinv) {
    __shared__ int lcnt[256];
    __shared__ int s[256];
    __shared__ int lcur[256];
    __shared__ int lde[DCAP];
    const int b = blockIdx.x;
    const int tid = threadIdx.x;
    lcnt[tid] = 0;
    __syncthreads();
    const int base = binbase[b];
    const int nb = min(binbase[b + 1] - base, DCAP);
    for (int j = tid; j < nb; j += 256) atomicAdd(&lcnt[rec[base + j] >> 24], 1);
    __syncthreads();
    int cv = lcnt[tid];
    s[tid] = cv;
    __syncthreads();
    int acc = cv;
    for (int d = 1; d < 256; d <<= 1) {
        int add = (tid >= d) ? s[tid - d] : 0;
        __syncthreads();
        acc += add;
        s[tid] = acc;
        __syncthreads();
    }
    int excl = acc - cv;
    lcur[tid] = excl;
    const int node = (b << 8) + tid;
    if (node < NN) {
        cnt[node] = cv;
        cursor[node] = base + excl + cv;            // END cursor (start = end - cnt)
        dinv[node] = rsqrtf((float)(cv + 1));       // +1 self-loop
    }
    __syncthreads();
    for (int j = tid; j < nb; j += 256) {
        unsigned v = rec[base + j];
        int pos = atomicAdd(&lcur[v >> 24], 1);     // LDS atomic
        lde[pos] = (int)(v & 0xFFFFFFu);
    }
    __syncthreads();
    for (int j = tid; j < nb; j += 256) eidx[base + j] = lde[j];
}

// ---- fused prep: xh[i] = bf16(x[i]*dinv[i]) ; pack W1,W2. float4-vectorized ----
__global__ void k_prep(const float4* __restrict__ x, const float* __restrict__ dinv,
                       uint2* __restrict__ xh,
                       const float* __restrict__ W1, const float* __restrict__ W2,
                       __hip_bfloat16* __restrict__ W1p, __hip_bfloat16* __restrict__ W2p) {
    if (blockIdx.x < XB2) {
        int idx = blockIdx.x * 256 + threadIdx.x;   // NN*32 float4s, exact multiple
        float d = dinv[idx >> 5];
        float4 v = x[idx];
        uint2 o;
        o.x = (unsigned)f2bf(v.x * d) | ((unsigned)f2bf(v.y * d) << 16);
        o.y = (unsigned)f2bf(v.z * d) | ((unsigned)f2bf(v.w * d) << 16);
        xh[idx] = o;
    } else {
        int idx = (blockIdx.x - XB2) * 256 + threadIdx.x;
        if (idx < F1 * F2) {
            int k = idx / F2, col = idx - (idx / F2) * F2;
            int k8 = k >> 3, j = k & 7;
            W1p[((size_t)(k8 * F2 + col) << 3) + j] = __float2bfloat16(W1[(size_t)k * F2 + col]);
        } else if (idx < F1 * F2 + F2 * 48) {
            int i2 = idx - F1 * F2;
            int k = i2 / 48, col = i2 - (i2 / 48) * 48;
            int k8 = k >> 3, j = k & 7;
            float v = (col < F3) ? W2[(size_t)k * F3 + col] : 0.0f;
            W2p[((size_t)(k8 * 48 + col) << 3) + j] = __float2bfloat16(v);
        }
    }
}

// ---- layer-1 pull aggregation: round-0 structure (known-good, 3.63 TB/s).
// One wave per node; lane = feature-dword; 8 full-row (256B) gathers in flight. ----
__global__ __launch_bounds__(256) void k_agg1(const int* __restrict__ cursor,
                                              const int* __restrict__ cnt,
                                              const int* __restrict__ eidx,
                                              const float* __restrict__ dinv,
                                              const unsigned* __restrict__ xh,
                                              unsigned* __restrict__ agg) {
    int node = blockIdx.x * 4 + (threadIdx.x >> 6);
    int lane = threadIdx.x & 63;
    if (node >= NN) return;
    unsigned vs = xh[((size_t)node << 6) + lane];
    float a0 = bflo(vs), a1 = bfhi(vs);
    int n = cnt[node];
    int s = cursor[node] - n;
    int k = 0;
    for (; k + 7 < n; k += 8) {
        int r0 = eidx[s + k + 0], r1 = eidx[s + k + 1];
        int r2 = eidx[s + k + 2], r3 = eidx[s + k + 3];
        int r4 = eidx[s + k + 4], r5 = eidx[s + k + 5];
        int r6 = eidx[s + k + 6], r7 = eidx[s + k + 7];
        unsigned v0 = xh[((size_t)r0 << 6) + lane];
        unsigned v1 = xh[((size_t)r1 << 6) + lane];
        unsigned v2 = xh[((size_t)r2 << 6) + lane];
        unsigned v3 = xh[((size_t)r3 << 6) + lane];
        unsigned v4 = xh[((size_t)r4 << 6) + lane];
        unsigned v5 = xh[((size_t)r5 << 6) + lane];
        unsigned v6 = xh[((size_t)r6 << 6) + lane];
        unsigned v7 = xh[((size_t)r7 << 6) + lane];
        a0 += bflo(v0); a1 += bfhi(v0);
        a0 += bflo(v1); a1 += bfhi(v1);
        a0 += bflo(v2); a1 += bfhi(v2);
        a0 += bflo(v3); a1 += bfhi(v3);
        a0 += bflo(v4); a1 += bfhi(v4);
        a0 += bflo(v5); a1 += bfhi(v5);
        a0 += bflo(v6); a1 += bfhi(v6);
        a0 += bflo(v7); a1 += bfhi(v7);
    }
    for (; k + 3 < n; k += 4) {
        int r0 = eidx[s + k + 0], r1 = eidx[s + k + 1];
        int r2 = eidx[s + k + 2], r3 = eidx[s + k + 3];
        unsigned v0 = xh[((size_t)r0 << 6) + lane];
        unsigned v1 = xh[((size_t)r1 << 6) + lane];
        unsigned v2 = xh[((size_t)r2 << 6) + lane];
        unsigned v3 = xh[((size_t)r3 << 6) + lane];
        a0 += bflo(v0); a1 += bfhi(v0);
        a0 += bflo(v1); a1 += bfhi(v1);
        a0 += bflo(v2); a1 += bfhi(v2);
        a0 += bflo(v3); a1 += bfhi(v3);
    }
    for (; k < n; ++k) {
        unsigned v0 = xh[((size_t)eidx[s + k] << 6) + lane];
        a0 += bflo(v0); a1 += bfhi(v0);
    }
    float d = dinv[node];
    agg[((size_t)node << 6) + lane] = (unsigned)f2bf(a0 * d) | ((unsigned)f2bf(a1 * d) << 16);
}

// ---- fused MFMA GEMM1 + ReLU + GEMM2; tg rows PACKED to 40 bf16 (80B, 16B-aligned) ----
__global__ __launch_bounds__(256) void k_gemm_mfma(
    const __hip_bfloat16* __restrict__ agg, const __hip_bfloat16* __restrict__ W1p,
    const float* __restrict__ b1, const __hip_bfloat16* __restrict__ W2p,
    const float* __restrict__ dinv, unsigned short* __restrict__ tg) {
    __shared__ __hip_bfloat16 h_s[MROWS][F2 + 8];   // 33 KB
    const int i0   = blockIdx.x * MROWS;
    const int wave = threadIdx.x >> 6;
    const int lane = threadIdx.x & 63;
    const int m = lane & 15, q = lane >> 4;
    const int rowA = i0 + wave * 16 + m;

    f32x4 acc[16];
#pragma unroll
    for (int c = 0; c < 16; ++c) acc[c] = (f32x4){0.f, 0.f, 0.f, 0.f};

#pragma unroll
    for (int s = 0; s < 4; ++s) {           // k = 32s + 8q + j
        bf16x8 a;
#pragma unroll
        for (int j = 0; j < 8; ++j) a[j] = (__bf16)0.0f;
        if (rowA < NN) a = *(const bf16x8*)(agg + (size_t)rowA * F1 + s * 32 + q * 8);
        const __hip_bfloat16* bp = W1p + ((size_t)(4 * s + q) * F2) * 8;
#pragma unroll
        for (int c = 0; c < 16; ++c) {
            bf16x8 b = *(const bf16x8*)(bp + ((size_t)(c * 16 + m) << 3));
            acc[c] = __builtin_amdgcn_mfma_f32_16x16x32_bf16(a, b, acc[c], 0, 0, 0);
        }
    }

#pragma unroll
    for (int c = 0; c < 16; ++c) {
        int col = c * 16 + m;
        float bj = b1[col];
#pragma unroll
        for (int r = 0; r < 4; ++r) {
            int lr = wave * 16 + q * 4 + r;
            h_s[lr][col] = __float2bfloat16(fmaxf(acc[c][r] + bj, 0.0f));
        }
    }
    __syncthreads();

    f32x4 acc2[3];
#pragma unroll
    for (int c = 0; c < 3; ++c) acc2[c] = (f32x4){0.f, 0.f, 0.f, 0.f};

#pragma unroll
    for (int s = 0; s < 8; ++s) {
        bf16x8 a = *(const bf16x8*)(&h_s[wave * 16 + m][s * 32 + q * 8]);
        const __hip_bfloat16* bp = W2p + ((size_t)(4 * s + q) * 48) * 8;
#pragma unroll
        for (int c = 0; c < 3; ++c) {
            bf16x8 b = *(const bf16x8*)(bp + ((size_t)(c * 16 + m) << 3));
            acc2[c] = __builtin_amdgcn_mfma_f32_16x16x32_bf16(a, b, acc2[c], 0, 0, 0);
        }
    }

#pragma unroll
    for (int c = 0; c < 3; ++c) {
        int col = c * 16 + m;
        if (col < F3) {
#pragma unroll
            for (int r = 0; r < 4; ++r) {
                int grow = i0 + wave * 16 + q * 4 + r;
                if (grow < NN)
                    tg[(size_t)grow * F3 + col] = f2bf(acc2[c][r] * dinv[grow]);
            }
        }
    }
}

// ---- layer-2 pull aggregation: 2 nodes/wave, dword-per-lane over packed 80B rows.
// Per half: lane t<20 loads dword t (2 features). 8 gathers in flight per half. ----
__global__ __launch_bounds__(256) void k_agg2(const int* __restrict__ cursor,
                                              const int* __restrict__ cnt,
                                              const int* __restrict__ eidx,
                                              const float* __restrict__ dinv,
                                              const unsigned short* __restrict__ tg,
                                              const float* __restrict__ b2,
                                              float* __restrict__ out) {
    const int wave = threadIdx.x >> 6;
    const int lane = threadIdx.x & 63;
    const int h = lane >> 5;                        // which node of the pair
    const int t = lane & 31;                        // dword index in row (t<20 active)
    const int node = blockIdx.x * 8 + wave * 2 + h; // NN%8==0 -> always valid
    const unsigned* __restrict__ tgw = (const unsigned*)tg;
    if (t >= 20) return;                            // 80B row = 20 dwords

    unsigned vs = tgw[(size_t)node * 20 + t];       // self term
    float a0 = bflo(vs), a1 = bfhi(vs);
    const int n = cnt[node];
    const int s = cursor[node] - n;
    int k = 0;
    for (; k + 7 < n; k += 8) {
        int r0 = eidx[s + k + 0], r1 = eidx[s + k + 1];
        int r2 = eidx[s + k + 2], r3 = eidx[s + k + 3];
        int r4 = eidx[s + k + 4], r5 = eidx[s + k + 5];
        int r6 = eidx[s + k + 6], r7 = eidx[s + k + 7];
        unsigned v0 = tgw[(size_t)r0 * 20 + t];
        unsigned v1 = tgw[(size_t)r1 * 20 + t];
        unsigned v2 = tgw[(size_t)r2 * 20 + t];
        unsigned v3 = tgw[(size_t)r3 * 20 + t];
        unsigned v4 = tgw[(size_t)r4 * 20 + t];
        unsigned v5 = tgw[(size_t)r5 * 20 + t];
        unsigned v6 = tgw[(size_t)r6 * 20 + t];
        unsigned v7 = tgw[(size_t)r7 * 20 + t];
        a0 += bflo(v0); a1 += bfhi(v0);
        a0 += bflo(v1); a1 += bfhi(v1);
        a0 += bflo(v2); a1 += bfhi(v2);
        a0 += bflo(v3); a1 += bfhi(v3);
        a0 += bflo(v4); a1 += bfhi(v4);
        a0 += bflo(v5); a1 += bfhi(v5);
        a0 += bflo(v6); a1 += bfhi(v6);
        a0 += bflo(v7); a1 += bfhi(v7);
    }
    for (; k + 3 < n; k += 4) {
        int r0 = eidx[s + k + 0], r1 = eidx[s + k + 1];
        int r2 = eidx[s + k + 2], r3 = eidx[s + k + 3];
        unsigned v0 = tgw[(size_t)r0 * 20 + t];
        unsigned v1 = tgw[(size_t)r1 * 20 + t];
        unsigned v2 = tgw[(size_t)r2 * 20 + t];
        unsigned v3 = tgw[(size_t)r3 * 20 + t];
        a0 += bflo(v0); a1 += bfhi(v0);
        a0 += bflo(v1); a1 += bfhi(v1);
        a0 += bflo(v2); a1 += bfhi(v2);
        a0 += bflo(v3); a1 += bfhi(v3);
    }
    for (; k < n; ++k) {
        unsigned v0 = tgw[(size_t)eidx[s + k] * 20 + t];
        a0 += bflo(v0); a1 += bfhi(v0);
    }
    float d = dinv[node];
    float2 bb = ((const float2*)b2)[t];
    float2 o;
    o.x = a0 * d + bb.x;
    o.y = a1 * d + bb.y;
    ((float2*)(out + (size_t)node * F3))[t] = o;
}

extern "C" void kernel_launch(void* const* d_in, const int* in_sizes, int n_in,
                              void* d_out, int out_size, void* d_ws, size_t ws_size,
                              hipStream_t stream) {
    const float* x  = (const float*)d_in[0];
    const int*   ei = (const int*)d_in[1];
    const float* W1 = (const float*)d_in[2];
    const float* b1 = (const float*)d_in[3];
    const float* W2 = (const float*)d_in[4];
    const float* b2 = (const float*)d_in[5];
    float* out = (float*)d_out;

    const int* row = ei;
    const int* col = ei + EE;

    // ws: cnt[N] | cursor[N] | dinv[N] | hist[NBUK*NBLK] | bintot | binbase
    //     | eidx[E] | xh[N*64 u32] | agg[N*64 u32] | W1p | W2p         ~58 MB
    // overlays: rec (E u32) on agg (dead until k_agg1); tg (N*40 bf16 = 8MB,
    // packed 80B rows, 16B-aligned) on xh (dead after k_agg1).
    // slack +9: makes xh/agg/W1p 16B-aligned for uint4/bf16x8 loads.
    int* cnt     = (int*)d_ws;
    int* cursor  = cnt + NN;
    float* dinv  = (float*)(cursor + NN);
    int* hist    = (int*)(dinv + NN);
    int* bintot  = hist + NBUK * NBLK;
    int* binbase = bintot + NBUK;
    int* eidx    = binbase + (NBUK + 1) + 9;   // alignment slack -> xh % 16 == 0
    unsigned* xh  = (unsigned*)(eidx + EE);
    unsigned* agg = xh + (size_t)NN * 64;
    unsigned* rec = agg;                               // overlay
    unsigned short* tg = (unsigned short*)xh;          // overlay (packed, 8 MB)
    __hip_bfloat16* W1p = (__hip_bfloat16*)(agg + (size_t)NN * 64);
    __hip_bfloat16* W2p = W1p + (size_t)F1 * F2;

    k_hist    <<<NBLK, 256, 0, stream>>>(col, hist);
    k_scanbin <<<NBUK, NBLK, 0, stream>>>(hist, bintot);
    k_scanbase<<<1, 512, 0, stream>>>(bintot, binbase);
    k_scat    <<<NBLK, 256, 0, stream>>>(row, col, hist, binbase, rec);
    k_csr     <<<NBUK, 256, 0, stream>>>(binbase, rec, eidx, cnt, cursor, dinv);

    k_prep<<<XB2 + (F1 * F2 + F2 * 48 + 255) / 256, 256, 0, stream>>>(
        (const float4*)x, dinv, (uint2*)xh, W1, W2, W1p, W2p);

    k_agg1<<<(NN + 3) / 4, 256, 0, stream>>>(cursor, cnt, eidx, dinv, xh, agg);
    k_gemm_mfma<<<(NN + MROWS - 1) / MROWS, 256, 0, stream>>>(
        (const __hip_bfloat16*)agg, W1p, b1, W2p, dinv, tg);
    k_agg2<<<NN / 8, 256, 0, stream>>>(cursor, cnt, eidx, dinv, tg, b2, out);
}